// Round 2
// baseline (824.548 us; speedup 1.0000x reference)
//
#include <hip/hip_runtime.h>
#include <hip/hip_bf16.h>
#include <hip/hip_cooperative_groups.h>
#include <math.h>

namespace cg = cooperative_groups;

typedef float f32x4 __attribute__((ext_vector_type(4)));
typedef float f32x4u __attribute__((ext_vector_type(4))) __attribute__((aligned(4)));
typedef short s16x8 __attribute__((ext_vector_type(8)));

__device__ __forceinline__ float wave_reduce64(float v) {
#pragma unroll
    for (int m = 32; m > 0; m >>= 1) v += __shfl_xor(v, m, 64);
    return v;
}

__device__ __forceinline__ unsigned short f32_to_bf16_rn(float x) {
    unsigned int u = __float_as_uint(x);
    unsigned int r = (u + 0x7fffu + ((u >> 16) & 1u)) >> 16;
    return (unsigned short)r;
}
__device__ __forceinline__ float bf16_to_f32(unsigned short h) {
    return __uint_as_float(((unsigned int)h) << 16);
}

__device__ __forceinline__ void dma_row16(const float* gsrc, float* ldst) {
    // 64 lanes x 16B -> one contiguous 1KB LDS row at wave-uniform ldst
    __builtin_amdgcn_global_load_lds(
        (const __attribute__((address_space(1))) unsigned int*)gsrc,
        (__attribute__((address_space(3))) unsigned int*)ldst,
        16, 0, 0);
}

// ==================== FUSED cooperative kernel ====================
// 256 blocks x 512 threads (8 waves), 1 block/CU (LDS-forced), cooperative.
// Phase A: per-block redundant h0/h1 (W2 is L2/L3-resident), overlapped with
//          phase-B prologue DMAs.
// Phase B: verbatim verified 540MB DMA stream (waves 0-3 only).
// grid.sync -> Phase C: s[f] dot (8 waves) -> grid.sync ->
// Phase D: verbatim kD logic, 32 z-rows/block as two independent 4-wave
//          groups (same 8 waves/CU concurrency as the 512-block version).
// Dyn LDS: phase B: h_s[0,1088) | bufs[1088,34368) | h0[34368,35392) words.
//          phase D overlays: g_lds (18,432B) + red (55,296B).
__global__ __launch_bounds__(512, 2) void kF(
    const float* __restrict__ t, const float* __restrict__ zin,
    const float* __restrict__ W1, const float* __restrict__ B1,
    const float* __restrict__ W2, const float* __restrict__ B2,
    const float* __restrict__ Wwin, const float* __restrict__ bwin,
    const float* __restrict__ Wwout, const float* __restrict__ bwout,
    const float* __restrict__ Wb, const float* __restrict__ bb,
    const float* __restrict__ Wg, const float* __restrict__ bg,
    float* __restrict__ w_in, float* __restrict__ w_out,
    unsigned short* __restrict__ w_in_hi, unsigned short* __restrict__ w_in_lo,
    unsigned short* __restrict__ w_out_t,
    float* __restrict__ b_arr, float* __restrict__ gate,
    float* __restrict__ s, float* __restrict__ out) {
    extern __shared__ float smem[];
    float* h_s = smem;           // [0, 1088)
    float* bufs = smem + 1088;   // [1088, 34368)
    float* h0_p = smem + 34368;  // [34368, 35392)

    const int tid = threadIdx.x;
    const int w = tid >> 6, lane = tid & 63;
    const int bid = blockIdx.x;

    // ---- Phase B prologue: issue chunks k=0 (buf0), k=1 (buf1); waves 0-3 ----
    if (tid < 256) {
#pragma unroll
        for (int pk = 0; pk < 2; pk++) {
            const int ci = bid + pk * 256;
            const float* W; int row0;
            if (ci < 4096)      { W = Wwin;  row0 = ci * 64; }
            else if (ci < 8192) { W = Wwout; row0 = (ci - 4096) * 64; }
            else if (ci < 8224) { W = Wb;    row0 = (ci - 8192) * 64; }
            else                { W = Wg;    row0 = (ci - 8224) * 64; }
            const float* src = W + (size_t)(row0 + w * 16) * 256 + (lane << 2);
            float* dst = bufs + (size_t)((pk * 4 + w) * 16) * 260;
#pragma unroll
            for (int rr = 0; rr < 16; rr++) dma_row16(src + rr * 256, dst + rr * 260);
        }
    }

    // ---- Phase A: h0, then h1 into padded h_s (all 8 waves) ----
    {
        const float ts = t[0];
        for (int o = tid; o < 1024; o += 512)
            h0_p[o] = tanhf(W1[o] * ts + B1[o]);
        __syncthreads();
        for (int o = tid; o < 1024; o += 512) {
            const int k = o >> 8, n = o & 255;
            const float* w2p = W2 + ((size_t)o << 8);
            const float* h0k = h0_p + (k << 8);
            float ax = 0.f, ay = 0.f, az = 0.f, aw = 0.f;
#pragma unroll 8
            for (int m = 0; m < 256; m += 4) {
                f32x4 wv = *(const f32x4*)(w2p + m);
                f32x4 hv = *(const f32x4*)(h0k + m);
                ax += wv.x * hv.x; ay += wv.y * hv.y;
                az += wv.z * hv.z; aw += wv.w * hv.w;
            }
            float v = tanhf((ax + ay) + (az + aw) + B2[o]);
            h_s[k * 272 + ((n >> 6) * 68) + (n & 63)] = v;
        }
        __syncthreads();  // h ready (also drains prologue DMAs once; harmless)
    }

    // ---- Phase B: the 540 MB stream (waves 0-3 only; barrier-free loop) ----
    if (tid < 256) {
        const int r = lane >> 2, c = lane & 3;
        for (int k = 0;; k++) {
            const int cur = bid + k * 256;
            if (cur >= 8256) break;
            const int buf = k & 1;
            const bool has_next = (cur + 256) < 8256;
            if (has_next) asm volatile("s_waitcnt vmcnt(16)" ::: "memory");
            else          asm volatile("s_waitcnt vmcnt(0)" ::: "memory");

            int seg, row0;
            const float* bias;
            if (cur < 4096)      { seg = 0; row0 = cur * 64;          bias = bwin; }
            else if (cur < 8192) { seg = 1; row0 = (cur - 4096) * 64; bias = bwout; }
            else if (cur < 8224) { seg = 2; row0 = (cur - 8192) * 64; bias = bb; }
            else                 { seg = 3; row0 = (cur - 8224) * 64; bias = bg; }

            const float* rowp = bufs + (size_t)((buf * 4 + w) * 16 + r) * 260 + c * 64;
            const float* hp = h_s + seg * 272 + c * 68;
            float a0 = 0.f, a1 = 0.f;
#pragma unroll
            for (int j = 0; j < 16; j += 2) {
                f32x4 d0 = *(const f32x4*)(rowp + 4 * j);
                f32x4 h0 = *(const f32x4*)(hp + 4 * j);
                f32x4 d1 = *(const f32x4*)(rowp + 4 * j + 4);
                f32x4 h1v = *(const f32x4*)(hp + 4 * j + 4);
                a0 += d0.x * h0.x + d0.y * h0.y + d0.z * h0.z + d0.w * h0.w;
                a1 += d1.x * h1v.x + d1.y * h1v.y + d1.z * h1v.z + d1.w * h1v.w;
            }
            float acc = a0 + a1;
            acc += __shfl_xor(acc, 1, 64);
            acc += __shfl_xor(acc, 2, 64);

            if (c == 0) {
                const int idx = row0 + w * 16 + r;
                float v = acc + bias[idx];
                if (seg == 0) {
                    w_in[idx] = v;
                    unsigned short hi = f32_to_bf16_rn(v);
                    w_in_hi[idx] = hi;
                    w_in_lo[idx] = f32_to_bf16_rn(v - bf16_to_f32(hi));
                } else if (seg == 1) {
                    w_out[idx] = v;
                    w_out_t[(size_t)(idx & 127) * 2048 + (idx >> 7)] = f32_to_bf16_rn(v);
                } else if (seg == 2) {
                    b_arr[idx] = v;
                } else {
                    gate[idx] = 1.f / (1.f + __expf(-v));
                }
            }

            asm volatile("s_waitcnt lgkmcnt(0)" ::: "memory");

            const int pf = cur + 512;
            if (pf < 8256) {
                const float* W; int prow0;
                if (pf < 4096)      { W = Wwin;  prow0 = pf * 64; }
                else if (pf < 8192) { W = Wwout; prow0 = (pf - 4096) * 64; }
                else if (pf < 8224) { W = Wb;    prow0 = (pf - 8192) * 64; }
                else                { W = Wg;    prow0 = (pf - 8224) * 64; }
                const float* src = W + (size_t)(prow0 + w * 16) * 256 + (lane << 2);
                float* dst = bufs + (size_t)((buf * 4 + w) * 16) * 260;
#pragma unroll
                for (int rr = 0; rr < 16; rr++) dma_row16(src + rr * 256, dst + rr * 260);
            }
        }
    }

    __threadfence();
    cg::this_grid().sync();

    // ---- Phase C: s[f] = dot(w_in[f,:], w_out[f,:]) (8 waves -> 8 f/block) ----
    {
        const int f = bid * 8 + w;
        float2 a = *(const float2*)(w_in + (size_t)f * 128 + lane * 2);
        float2 b = *(const float2*)(w_out + (size_t)f * 128 + lane * 2);
        float p = a.x * b.x + a.y * b.y;
        p = wave_reduce64(p);
        if (lane == 0) s[f] = p;
    }

    __threadfence();
    cg::this_grid().sync();

    // ---- Phase D: fused h/g/dz/trace via MFMA; 32 rows/block in 2 groups ----
    {
        unsigned short* g_lds = (unsigned short*)smem;  // [2][4][16][72] u16
        float* red = smem + 4608;                       // [2][3][64][36] f32

        const int g = w >> 2, w4 = w & 3;
        const int q = lane >> 4, lm = lane & 15;
        const int b0 = bid * 32 + g * 16;
        const int brow = b0 + lm;

        s16x8 zh[4], zl[4];
#pragma unroll
        for (int kt = 0; kt < 4; kt++) {
            const float* zp = zin + (size_t)brow * 129 + kt * 32 + q * 8;
            f32x4u z0 = *(const f32x4u*)(zp);
            f32x4u z1 = *(const f32x4u*)(zp + 4);
            float zv[8] = {z0.x, z0.y, z0.z, z0.w, z1.x, z1.y, z1.z, z1.w};
#pragma unroll
            for (int j = 0; j < 8; j++) {
                unsigned short hi = f32_to_bf16_rn(zv[j]);
                zh[kt][j] = (short)hi;
                zl[kt][j] = (short)f32_to_bf16_rn(zv[j] - bf16_to_f32(hi));
            }
        }

        f32x4 acc2[8];
#pragma unroll
        for (int ct = 0; ct < 8; ct++) acc2[ct] = (f32x4){0.f, 0.f, 0.f, 0.f};
        float tr[4] = {0.f, 0.f, 0.f, 0.f};

        for (int ch = 0; ch < 8; ch++) {
            const int f0 = w4 * 512 + ch * 64;
#pragma unroll
            for (int nt = 0; nt < 4; nt++) {
                const int fc = f0 + nt * 16 + lm;
                const unsigned short* ph = w_in_hi + (size_t)fc * 128;
                const unsigned short* pl = w_in_lo + (size_t)fc * 128;
                f32x4 acc1 = {0.f, 0.f, 0.f, 0.f};
#pragma unroll
                for (int kt = 0; kt < 4; kt++) {
                    s16x8 bh = *(const s16x8*)(ph + kt * 32 + q * 8);
                    s16x8 bl = *(const s16x8*)(pl + kt * 32 + q * 8);
                    acc1 = __builtin_amdgcn_mfma_f32_16x16x32_bf16(zh[kt], bh, acc1, 0, 0, 0);
                    acc1 = __builtin_amdgcn_mfma_f32_16x16x32_bf16(zh[kt], bl, acc1, 0, 0, 0);
                    acc1 = __builtin_amdgcn_mfma_f32_16x16x32_bf16(zl[kt], bh, acc1, 0, 0, 0);
                }
                const float gv = gate[fc], bv = b_arr[fc], sv = s[fc];
#pragma unroll
                for (int i = 0; i < 4; i++) {
                    float pre = acc1[i] + bv;
                    float e = __expf(2.f * pre);
                    float th = 1.f - 2.f * __builtin_amdgcn_rcpf(e + 1.f);
                    float gg = th * gv;
                    tr[i] += (1.f - th * th) * gv * sv;
                    g_lds[((g * 4 + w4) * 16 + (q * 4 + i)) * 72 + nt * 16 + lm] = f32_to_bf16_rn(gg);
                }
            }
#pragma unroll
            for (int kt2 = 0; kt2 < 2; kt2++) {
                s16x8 af = *(const s16x8*)&g_lds[((g * 4 + w4) * 16 + lm) * 72 + kt2 * 32 + q * 8];
#pragma unroll
                for (int ct = 0; ct < 8; ct++) {
                    s16x8 bf = *(const s16x8*)(w_out_t + (size_t)(ct * 16 + lm) * 2048 + f0 + kt2 * 32 + q * 8);
                    acc2[ct] = __builtin_amdgcn_mfma_f32_16x16x32_bf16(af, bf, acc2[ct], 0, 0, 0);
                }
            }
        }

        if (w4 != 0) {
#pragma unroll
            for (int ct = 0; ct < 8; ct++)
                *(f32x4*)&red[(((g * 3 + (w4 - 1)) * 64 + lane)) * 36 + ct * 4] = acc2[ct];
            *(f32x4*)&red[(((g * 3 + (w4 - 1)) * 64 + lane)) * 36 + 32] = (f32x4){tr[0], tr[1], tr[2], tr[3]};
        }
        __syncthreads();
        if (w4 == 0) {
#pragma unroll
            for (int ww = 0; ww < 3; ww++) {
#pragma unroll
                for (int ct = 0; ct < 8; ct++) {
                    f32x4 o = *(const f32x4*)&red[(((g * 3 + ww) * 64 + lane)) * 36 + ct * 4];
                    acc2[ct].x += o.x; acc2[ct].y += o.y; acc2[ct].z += o.z; acc2[ct].w += o.w;
                }
                f32x4 to = *(const f32x4*)&red[(((g * 3 + ww) * 64 + lane)) * 36 + 32];
                tr[0] += to.x; tr[1] += to.y; tr[2] += to.z; tr[3] += to.w;
            }

            const float inv = 1.f / 2048.f;
#pragma unroll
            for (int ct = 0; ct < 8; ct++)
#pragma unroll
                for (int i = 0; i < 4; i++)
                    out[(size_t)(b0 + q * 4 + i) * 129 + ct * 16 + lm] = acc2[ct][i] * inv;
#pragma unroll
            for (int i = 0; i < 4; i++) {
                float t2 = tr[i];
                t2 += __shfl_xor(t2, 1, 64);
                t2 += __shfl_xor(t2, 2, 64);
                t2 += __shfl_xor(t2, 4, 64);
                t2 += __shfl_xor(t2, 8, 64);
                if (lm == 0) out[(size_t)(b0 + q * 4 + i) * 129 + 128] = -t2 * inv;
            }
        }
    }
}

// ==================== Fallback: proven 4-kernel pipeline ====================

__global__ __launch_bounds__(256) void kA(const float* __restrict__ t,
                                          const float* __restrict__ W1, const float* __restrict__ B1,
                                          const float* __restrict__ W2, const float* __restrict__ B2,
                                          float* __restrict__ h1) {
    const int tid = threadIdx.x;
    const int wave = (blockIdx.x << 2) + (tid >> 6);
    const int lane = tid & 63;
    const int k = wave >> 8, n = wave & 255;
    const float ts = t[0];
    const int m0 = lane << 2;
    f32x4 w1 = *(const f32x4*)(W1 + k * 256 + m0);
    f32x4 b1 = *(const f32x4*)(B1 + k * 256 + m0);
    f32x4 w2 = *(const f32x4*)(W2 + (size_t)(k * 256 + n) * 256 + m0);
    float p = 0.f;
    p += w2.x * tanhf(w1.x * ts + b1.x);
    p += w2.y * tanhf(w1.y * ts + b1.y);
    p += w2.z * tanhf(w1.z * ts + b1.z);
    p += w2.w * tanhf(w1.w * ts + b1.w);
    p = wave_reduce64(p);
    if (lane == 0) h1[k * 256 + n] = tanhf(p + B2[k * 256 + n]);
}

__global__ __launch_bounds__(256) void kB_dma(const float* __restrict__ Wwin, const float* __restrict__ bwin,
                                              const float* __restrict__ Wwout, const float* __restrict__ bwout,
                                              const float* __restrict__ Wb, const float* __restrict__ bb,
                                              const float* __restrict__ Wg, const float* __restrict__ bg,
                                              const float* __restrict__ h1,
                                              float* __restrict__ w_in, float* __restrict__ w_out,
                                              unsigned short* __restrict__ w_in_hi, unsigned short* __restrict__ w_in_lo,
                                              unsigned short* __restrict__ w_out_t,
                                              float* __restrict__ b_arr, float* __restrict__ gate) {
    extern __shared__ float smem[];
    float* h_s = smem;
    float* bufs = smem + 1088;

    const int tid = threadIdx.x;
    const int w = tid >> 6, lane = tid & 63;

    {
        const int seg = tid >> 6, q = (tid >> 4) & 3, i = tid & 15;
        f32x4 hv = *(const f32x4*)(h1 + seg * 256 + q * 64 + i * 4);
        *(f32x4*)(h_s + seg * 272 + q * 68 + i * 4) = hv;
    }

    const int r = lane >> 2, c = lane & 3;

#pragma unroll
    for (int pk = 0; pk < 2; pk++) {
        const int ci = blockIdx.x + pk * 256;
        const float* W; int row0;
        if (ci < 4096)      { W = Wwin;  row0 = ci * 64; }
        else if (ci < 8192) { W = Wwout; row0 = (ci - 4096) * 64; }
        else if (ci < 8224) { W = Wb;    row0 = (ci - 8192) * 64; }
        else                { W = Wg;    row0 = (ci - 8224) * 64; }
        const float* src = W + (size_t)(row0 + w * 16) * 256 + (lane << 2);
        float* dst = bufs + (size_t)((pk * 4 + w) * 16) * 260;
#pragma unroll
        for (int rr = 0; rr < 16; rr++) dma_row16(src + rr * 256, dst + rr * 260);
    }

    __syncthreads();

    for (int k = 0;; k++) {
        const int cur = blockIdx.x + k * 256;
        if (cur >= 8256) break;
        const int buf = k & 1;
        const bool has_next = (cur + 256) < 8256;
        if (has_next) asm volatile("s_waitcnt vmcnt(16)" ::: "memory");
        else          asm volatile("s_waitcnt vmcnt(0)" ::: "memory");

        int seg, row0;
        const float* bias;
        if (cur < 4096)      { seg = 0; row0 = cur * 64;          bias = bwin; }
        else if (cur < 8192) { seg = 1; row0 = (cur - 4096) * 64; bias = bwout; }
        else if (cur < 8224) { seg = 2; row0 = (cur - 8192) * 64; bias = bb; }
        else                 { seg = 3; row0 = (cur - 8224) * 64; bias = bg; }

        const float* rowp = bufs + (size_t)((buf * 4 + w) * 16 + r) * 260 + c * 64;
        const float* hp = h_s + seg * 272 + c * 68;
        float a0 = 0.f, a1 = 0.f;
#pragma unroll
        for (int j = 0; j < 16; j += 2) {
            f32x4 d0 = *(const f32x4*)(rowp + 4 * j);
            f32x4 h0 = *(const f32x4*)(hp + 4 * j);
            f32x4 d1 = *(const f32x4*)(rowp + 4 * j + 4);
            f32x4 h1v = *(const f32x4*)(hp + 4 * j + 4);
            a0 += d0.x * h0.x + d0.y * h0.y + d0.z * h0.z + d0.w * h0.w;
            a1 += d1.x * h1v.x + d1.y * h1v.y + d1.z * h1v.z + d1.w * h1v.w;
        }
        float acc = a0 + a1;
        acc += __shfl_xor(acc, 1, 64);
        acc += __shfl_xor(acc, 2, 64);

        if (c == 0) {
            const int idx = row0 + w * 16 + r;
            float v = acc + bias[idx];
            if (seg == 0) {
                w_in[idx] = v;
                unsigned short hi = f32_to_bf16_rn(v);
                w_in_hi[idx] = hi;
                w_in_lo[idx] = f32_to_bf16_rn(v - bf16_to_f32(hi));
            } else if (seg == 1) {
                w_out[idx] = v;
                w_out_t[(size_t)(idx & 127) * 2048 + (idx >> 7)] = f32_to_bf16_rn(v);
            } else if (seg == 2) {
                b_arr[idx] = v;
            } else {
                gate[idx] = 1.f / (1.f + __expf(-v));
            }
        }

        asm volatile("s_waitcnt lgkmcnt(0)" ::: "memory");

        const int pf = cur + 512;
        if (pf < 8256) {
            const float* W; int prow0;
            if (pf < 4096)      { W = Wwin;  prow0 = pf * 64; }
            else if (pf < 8192) { W = Wwout; prow0 = (pf - 4096) * 64; }
            else if (pf < 8224) { W = Wb;    prow0 = (pf - 8192) * 64; }
            else                { W = Wg;    prow0 = (pf - 8224) * 64; }
            const float* src = W + (size_t)(prow0 + w * 16) * 256 + (lane << 2);
            float* dst = bufs + (size_t)((buf * 4 + w) * 16) * 260;
#pragma unroll
            for (int rr = 0; rr < 16; rr++) dma_row16(src + rr * 256, dst + rr * 260);
        }
    }
}

__global__ __launch_bounds__(256) void kC(const float* __restrict__ w_in, const float* __restrict__ w_out,
                                          float* __restrict__ s) {
    const int f = (blockIdx.x << 2) + (threadIdx.x >> 6);
    const int lane = threadIdx.x & 63;
    float2 a = *(const float2*)(w_in + (size_t)f * 128 + lane * 2);
    float2 b = *(const float2*)(w_out + (size_t)f * 128 + lane * 2);
    float p = a.x * b.x + a.y * b.y;
    p = wave_reduce64(p);
    if (lane == 0) s[f] = p;
}

__global__ __launch_bounds__(256) void kD(const float* __restrict__ zin,
                                          const unsigned short* __restrict__ w_in_hi,
                                          const unsigned short* __restrict__ w_in_lo,
                                          const unsigned short* __restrict__ w_out_t,
                                          const float* __restrict__ b_arr, const float* __restrict__ gate,
                                          const float* __restrict__ s, float* __restrict__ out) {
    __shared__ __attribute__((aligned(16))) unsigned short g_lds[4][16][72];
    __shared__ __attribute__((aligned(16))) float red[3][64][36];

    const int tid = threadIdx.x;
    const int w = tid >> 6, lane = tid & 63;
    const int q = lane >> 4, lm = lane & 15;
    const int b0 = blockIdx.x * 16;
    const int brow = b0 + lm;

    s16x8 zh[4], zl[4];
#pragma unroll
    for (int kt = 0; kt < 4; kt++) {
        const float* zp = zin + (size_t)brow * 129 + kt * 32 + q * 8;
        f32x4u z0 = *(const f32x4u*)(zp);
        f32x4u z1 = *(const f32x4u*)(zp + 4);
        float zv[8] = {z0.x, z0.y, z0.z, z0.w, z1.x, z1.y, z1.z, z1.w};
#pragma unroll
        for (int j = 0; j < 8; j++) {
            unsigned short hi = f32_to_bf16_rn(zv[j]);
            zh[kt][j] = (short)hi;
            zl[kt][j] = (short)f32_to_bf16_rn(zv[j] - bf16_to_f32(hi));
        }
    }

    f32x4 acc2[8];
#pragma unroll
    for (int ct = 0; ct < 8; ct++) acc2[ct] = (f32x4){0.f, 0.f, 0.f, 0.f};
    float tr[4] = {0.f, 0.f, 0.f, 0.f};

    for (int ch = 0; ch < 8; ch++) {
        const int f0 = w * 512 + ch * 64;
#pragma unroll
        for (int nt = 0; nt < 4; nt++) {
            const int fc = f0 + nt * 16 + lm;
            const unsigned short* ph = w_in_hi + (size_t)fc * 128;
            const unsigned short* pl = w_in_lo + (size_t)fc * 128;
            f32x4 acc1 = {0.f, 0.f, 0.f, 0.f};
#pragma unroll
            for (int kt = 0; kt < 4; kt++) {
                s16x8 bh = *(const s16x8*)(ph + kt * 32 + q * 8);
                s16x8 bl = *(const s16x8*)(pl + kt * 32 + q * 8);
                acc1 = __builtin_amdgcn_mfma_f32_16x16x32_bf16(zh[kt], bh, acc1, 0, 0, 0);
                acc1 = __builtin_amdgcn_mfma_f32_16x16x32_bf16(zh[kt], bl, acc1, 0, 0, 0);
                acc1 = __builtin_amdgcn_mfma_f32_16x16x32_bf16(zl[kt], bh, acc1, 0, 0, 0);
            }
            const float gv = gate[fc], bv = b_arr[fc], sv = s[fc];
#pragma unroll
            for (int i = 0; i < 4; i++) {
                float pre = acc1[i] + bv;
                float e = __expf(2.f * pre);
                float th = 1.f - 2.f * __builtin_amdgcn_rcpf(e + 1.f);
                float g = th * gv;
                tr[i] += (1.f - th * th) * gv * sv;
                g_lds[w][q * 4 + i][nt * 16 + lm] = f32_to_bf16_rn(g);
            }
        }
#pragma unroll
        for (int kt2 = 0; kt2 < 2; kt2++) {
            s16x8 af = *(const s16x8*)&g_lds[w][lm][kt2 * 32 + q * 8];
#pragma unroll
            for (int ct = 0; ct < 8; ct++) {
                s16x8 bf = *(const s16x8*)(w_out_t + (size_t)(ct * 16 + lm) * 2048 + f0 + kt2 * 32 + q * 8);
                acc2[ct] = __builtin_amdgcn_mfma_f32_16x16x32_bf16(af, bf, acc2[ct], 0, 0, 0);
            }
        }
    }

    if (w != 0) {
#pragma unroll
        for (int ct = 0; ct < 8; ct++) *(f32x4*)&red[w - 1][lane][ct * 4] = acc2[ct];
        *(f32x4*)&red[w - 1][lane][32] = (f32x4){tr[0], tr[1], tr[2], tr[3]};
    }
    __syncthreads();
    if (w == 0) {
#pragma unroll
        for (int ww = 0; ww < 3; ww++) {
#pragma unroll
            for (int ct = 0; ct < 8; ct++) {
                f32x4 o = *(const f32x4*)&red[ww][lane][ct * 4];
                acc2[ct].x += o.x; acc2[ct].y += o.y; acc2[ct].z += o.z; acc2[ct].w += o.w;
            }
            f32x4 to = *(const f32x4*)&red[ww][lane][32];
            tr[0] += to.x; tr[1] += to.y; tr[2] += to.z; tr[3] += to.w;
        }

        const float inv = 1.f / 2048.f;
#pragma unroll
        for (int ct = 0; ct < 8; ct++)
#pragma unroll
            for (int i = 0; i < 4; i++)
                out[(size_t)(b0 + q * 4 + i) * 129 + ct * 16 + lm] = acc2[ct][i] * inv;
#pragma unroll
        for (int i = 0; i < 4; i++) {
            float t2 = tr[i];
            t2 += __shfl_xor(t2, 1, 64);
            t2 += __shfl_xor(t2, 2, 64);
            t2 += __shfl_xor(t2, 4, 64);
            t2 += __shfl_xor(t2, 8, 64);
            if (lm == 0) out[(size_t)(b0 + q * 4 + i) * 129 + 128] = -t2 * inv;
        }
    }
}

extern "C" void kernel_launch(void* const* d_in, const int* in_sizes, int n_in,
                              void* d_out, int out_size, void* d_ws, size_t ws_size,
                              hipStream_t stream) {
    const float* t     = (const float*)d_in[0];
    const float* z     = (const float*)d_in[1];
    const float* W1    = (const float*)d_in[2];
    const float* B1    = (const float*)d_in[3];
    const float* W2    = (const float*)d_in[4];
    const float* B2    = (const float*)d_in[5];
    const float* W3win = (const float*)d_in[6];
    const float* b3win = (const float*)d_in[7];
    const float* W3wo  = (const float*)d_in[8];
    const float* b3wo  = (const float*)d_in[9];
    const float* W3b   = (const float*)d_in[10];
    const float* b3b   = (const float*)d_in[11];
    const float* W3g   = (const float*)d_in[12];
    const float* b3g   = (const float*)d_in[13];
    float* out = (float*)d_out;

    float* h1    = (float*)d_ws;        // 1024
    float* w_in  = h1 + 1024;           // 262144
    float* w_out = w_in + 262144;       // 262144
    float* b_arr = w_out + 262144;      // 2048
    float* gate  = b_arr + 2048;        // 2048
    float* s     = gate + 2048;         // 2048
    unsigned short* w_in_hi = (unsigned short*)(s + 2048);  // 262144
    unsigned short* w_in_lo = w_in_hi + 262144;             // 262144
    unsigned short* w_out_t = w_in_lo + 262144;             // 262144

    // ---- Try the single fused cooperative kernel ----
    const int kf_lds = (1088 + 8 * 16 * 260 + 1024) * 4;  // 141,568 B
    hipError_t e = hipFuncSetAttribute((const void*)kF,
                                       hipFuncAttributeMaxDynamicSharedMemorySize, kf_lds);
    if (e == hipSuccess) {
        void* kargs[] = {
            (void*)&t, (void*)&z, (void*)&W1, (void*)&B1, (void*)&W2, (void*)&B2,
            (void*)&W3win, (void*)&b3win, (void*)&W3wo, (void*)&b3wo,
            (void*)&W3b, (void*)&b3b, (void*)&W3g, (void*)&b3g,
            (void*)&w_in, (void*)&w_out, (void*)&w_in_hi, (void*)&w_in_lo,
            (void*)&w_out_t, (void*)&b_arr, (void*)&gate, (void*)&s, (void*)&out};
        e = hipLaunchCooperativeKernel((const void*)kF, dim3(256), dim3(512),
                                       kargs, (unsigned int)kf_lds, stream);
    }
    if (e != hipSuccess) {
        // ---- Fallback: proven 4-kernel pipeline ----
        kA<<<256, 256, 0, stream>>>(t, W1, B1, W2, B2, h1);
        const int kb_lds = (1088 + 8 * 16 * 260) * 4;  // 137,472 B
        hipError_t attr_ok = hipFuncSetAttribute((const void*)kB_dma,
                                                 hipFuncAttributeMaxDynamicSharedMemorySize, kb_lds);
        if (attr_ok == hipSuccess) {
            kB_dma<<<256, 256, kb_lds, stream>>>(W3win, b3win, W3wo, b3wo, W3b, b3b, W3g, b3g, h1,
                                                 w_in, w_out, w_in_hi, w_in_lo, w_out_t, b_arr, gate);
        } else {
            kA<<<1, 1, 0, stream>>>(t, W1, B1, W2, B2, h1);  // unreachable placeholder
        }
        kC<<<512, 256, 0, stream>>>(w_in, w_out, s);
        kD<<<512, 256, 0, stream>>>(z, w_in_hi, w_in_lo, w_out_t, b_arr, gate, s, out);
    }
    (void)in_sizes; (void)n_in; (void)out_size; (void)ws_size;
}